// Round 10
// baseline (167.439 us; speedup 1.0000x reference)
//
#include <hip/hip_runtime.h>
#include <stdint.h>

// Problem constants: B=8, S=2048, D=256, DK=DV=128
typedef float    f32x4  __attribute__((ext_vector_type(4)));
typedef float    f32x16 __attribute__((ext_vector_type(16)));
typedef _Float16 f16x8  __attribute__((ext_vector_type(8)));
typedef _Float16 f16x4  __attribute__((ext_vector_type(4)));
typedef unsigned int u32x4 __attribute__((ext_vector_type(4)));

#define SPLIT 8
#define NTILES 8   // 8 kv-tiles of 32 keys = 256 keys per block

__device__ __forceinline__ f32x4 mfma16(f16x8 a, f16x8 b, f32x4 c) {
    return __builtin_amdgcn_mfma_f32_16x16x32_f16(a, b, c, 0, 0, 0);
}
__device__ __forceinline__ f32x16 mfma32(f16x8 a, f16x8 b, f32x16 c) {
    return __builtin_amdgcn_mfma_f32_32x32x16_f16(a, b, c, 0, 0, 0);
}
// async global->LDS DMA, 16 B/lane; LDS dest = base + lane*16 (wave-uniform base)
__device__ __forceinline__ void gll16(const _Float16* g, _Float16* l) {
    __builtin_amdgcn_global_load_lds(
        (const __attribute__((address_space(1))) void*)g,
        (__attribute__((address_space(3))) void*)l, 16, 0, 0);
}

// ---------------------------------------------------------------------------
// Kernel 0: transpose+convert W[256][128] f32 -> Wt[w][n][k]=[3][128][256] f16
// ---------------------------------------------------------------------------
__global__ __launch_bounds__(256) void prep_weights(
    const float* __restrict__ Wq, const float* __restrict__ Wk,
    const float* __restrict__ Wv, _Float16* __restrict__ wt) {
    __shared__ float Ls[64 * 65];
    const int bx = blockIdx.x;
    const int w  = bx >> 3, t = bx & 7;
    const int k0 = (t >> 1) * 64, n0 = (t & 1) * 64;
    const float* W = (w == 0) ? Wq : (w == 1) ? Wk : Wv;
    const int tid = threadIdx.x;
    #pragma unroll
    for (int i = 0; i < 16; i++) {
        int idx = i * 256 + tid;
        int r = idx >> 6, c = idx & 63;
        Ls[r * 65 + c] = W[(k0 + r) * 128 + n0 + c];
    }
    __syncthreads();
    #pragma unroll
    for (int i = 0; i < 16; i++) {
        int idx = i * 256 + tid;
        int r2 = idx >> 6, c2 = idx & 63;
        wt[w * 32768 + (n0 + r2) * 256 + k0 + c2] = (_Float16)Ls[c2 * 65 + r2];
    }
}

// ---------------------------------------------------------------------------
// Kernel 1: projections, barrier-free / LDS-free (weights L1/L2-resident).
// ---------------------------------------------------------------------------
__global__ __launch_bounds__(256) void proj_kernel(
    const float* __restrict__ xq, const float* __restrict__ xk,
    const float* __restrict__ xv, const _Float16* __restrict__ wt,
    const float* __restrict__ bq, const float* __restrict__ bk,
    const float* __restrict__ bv,
    _Float16* __restrict__ qo, _Float16* __restrict__ ko,
    _Float16* __restrict__ vtmp)
{
    const int mode = blockIdx.y;
    const float*    X    = mode == 0 ? xq : mode == 1 ? xk : xv;
    const float*    bias = mode == 0 ? bq : mode == 1 ? bk : bv;
    const _Float16* W    = wt + mode * 32768;
    _Float16*       Y    = mode == 0 ? qo : mode == 1 ? ko : vtmp;

    const int tid  = threadIdx.x;
    const int wave = tid >> 6, lane = tid & 63;
    const int ln   = lane & 15, qd = lane >> 4;
    const int row0 = blockIdx.x * 64 + wave * 16;

    const float*    xrow = X + (size_t)(row0 + ln) * 256 + qd * 8;
    const _Float16* wb   = W + ln * 256 + qd * 8;

    f32x4 acc[8];
    #pragma unroll
    for (int i = 0; i < 8; i++) acc[i] = (f32x4){0.f, 0.f, 0.f, 0.f};

    #pragma unroll
    for (int kk = 0; kk < 8; kk++) {
        f32x4 a0 = *(const f32x4*)(xrow + kk * 32);
        f32x4 a1 = *(const f32x4*)(xrow + kk * 32 + 4);
        f16x8 af;
        af[0] = (_Float16)a0[0]; af[1] = (_Float16)a0[1];
        af[2] = (_Float16)a0[2]; af[3] = (_Float16)a0[3];
        af[4] = (_Float16)a1[0]; af[5] = (_Float16)a1[1];
        af[6] = (_Float16)a1[2]; af[7] = (_Float16)a1[3];
        #pragma unroll
        for (int nt = 0; nt < 8; nt++) {
            f16x8 bf = *(const f16x8*)(wb + nt * 4096 + kk * 32);
            acc[nt] = mfma16(af, bf, acc[nt]);
        }
    }

    const float SC = 0.08838834764831845f * 1.4426950408889634f;
    #pragma unroll
    for (int nt = 0; nt < 8; nt++) {
        int col = nt * 16 + ln;
        float bb = bias[col];
        #pragma unroll
        for (int r = 0; r < 4; r++) {
            int orow = row0 + qd * 4 + r;
            float val = acc[nt][r] + bb;
            if (mode == 0) val *= SC;
            Y[(size_t)orow * 128 + col] = (_Float16)val;
        }
    }
}

// ---------------------------------------------------------------------------
// Kernel 1b: transpose V: vtmp[b][s][128] -> vt[b][128][2048].
// ---------------------------------------------------------------------------
__global__ __launch_bounds__(256) void transpose_v(
    const _Float16* __restrict__ vtmp, _Float16* __restrict__ vt)
{
    __shared__ __align__(16) _Float16 Ls[64 * 72];
    const int b  = blockIdx.z;
    const int s0 = blockIdx.x * 64;
    const int d0 = blockIdx.y * 64;
    const int tid = threadIdx.x;
    #pragma unroll
    for (int i = 0; i < 2; i++) {
        int idx = i * 256 + tid;
        int r = idx >> 3, c = (idx & 7) * 8;
        *(f16x8*)&Ls[r * 72 + c] =
            *(const f16x8*)(vtmp + (size_t)(b * 2048 + s0 + r) * 128 + d0 + c);
    }
    __syncthreads();
    #pragma unroll
    for (int i = 0; i < 2; i++) {
        int idx = i * 256 + tid;
        int dr = idx >> 3, sc8 = (idx & 7) * 8;
        f16x8 o;
        #pragma unroll
        for (int j = 0; j < 8; j++) o[j] = Ls[(sc8 + j) * 72 + dr];
        *(f16x8*)(vt + (size_t)(b * 128 + d0 + dr) * 2048 + s0 + sc8) = o;
    }
}

// ---------------------------------------------------------------------------
// Kernel 2: flash attention, 32x32x16 MFMA formulation.
// S^T = K Q^T per 32-kv tile: one 32x32 C-tile (16 f32/lane), lane owns ONE
// q-col (q = lane&31; lanes ln/ln+32 hold complementary kv rows -> 1 shuffle
// per softmax reduce). P^T stays in registers; its B-fragment for the PV
// 32x32x16 MFMA needs only a shfl_xor(^32) exchange per k-block (source
// reg-group = 2*kb2 + H_dest, source half = j>>2). Per-wave LDS traffic
// halves vs the 16x16 design (32 q per wave). KV tiles of 32, double-
// buffered via global_load_lds (K source XOR-swizzled by row&15; V linear).
// LDS 33792 B -> 3 blocks/CU at launch_bounds(256,3) (170-reg budget,
// ~132 live, no spill). Grid 1024 = 16 q0 x 8 b x SPLIT(8), XCD-pinned.
// ---------------------------------------------------------------------------
__global__ __launch_bounds__(256, 3) void attn_kernel(
    const _Float16* __restrict__ qp, const _Float16* __restrict__ kp,
    const _Float16* __restrict__ vtp, _Float16* __restrict__ opart,
    float2* __restrict__ ml)
{
    // decode: xcd fastest (round-robin pin), then q0, then group-high
    const int bid = blockIdx.x;
    const int gx  = bid & 7;
    const int q0i = (bid >> 3) & 15;
    const int gg  = bid >> 7;            // 0..7
    const int g   = gg * 8 + gx;         // 0..63 = b*SPLIT+z
    const int b   = g >> 3;
    const int z   = g & 7;
    const int q0  = q0i * 128;

    const int tid  = threadIdx.x;
    const int wave = tid >> 6, lane = tid & 63;
    const int ln   = lane & 31, h = lane >> 5;

    // staging: K dbuf at f16 ofs 0/4096 (32x128 each), V dbuf at 8192/12288
    // (128x32 each); epilogue reuses 0..16895 as 4 x (32 q x 132) per wave.
    __shared__ __align__(16) _Float16 smem[16896];

    // Q fragments: B-operand of S^T. qf[kb][j] = Q[q=ln][d=kb*16+h*8+j]
    const _Float16* qbase =
        qp + (size_t)(b * 2048 + q0 + wave * 32 + ln) * 128 + h * 8;
    f16x8 qf[8];
    #pragma unroll
    for (int kb = 0; kb < 8; kb++) qf[kb] = *(const f16x8*)(qbase + kb * 16);

    f32x16 o[4];                      // O^T: dv = dvb*32+(i&3)+8*(i>>2)+4h, q=ln
    #pragma unroll
    for (int i = 0; i < 4; i++) o[i] = (f32x16){};
    float m_run = -1e30f, l_run = 0.f;

    const _Float16* kbase = kp + (size_t)b * 2048 * 128;
    const _Float16* vbase = vtp + (size_t)b * 128 * 2048;
    const int kt0 = z * NTILES;

    // ---- async stage of one 32-kv K/V tile (4 gll per wave) ----
    auto stage = [&](int kt, int buf) {
        const _Float16* ks = kbase + (size_t)kt * 4096;   // 32 rows x 128
        const _Float16* vs = vbase + kt * 32;             // [128][2048] cols
        _Float16* kdst = smem + buf * 4096;
        _Float16* vdst = smem + 8192 + buf * 4096;
        #pragma unroll
        for (int j = 0; j < 2; j++) {
            int p  = wave * 128 + j * 64 + lane;          // granule 0..511
            int r  = p >> 4, c = p & 15;                  // K: 16 gran/row
            int cs = c ^ (r & 15);                        // XOR-swizzled src
            gll16(ks + r * 128 + cs * 8, kdst + (wave * 128 + j * 64) * 8);
            int rv = p >> 2, cv = p & 3;                  // V: 4 gran/row
            gll16(vs + (size_t)rv * 2048 + cv * 8, vdst + (wave * 128 + j * 64) * 8);
        }
    };

    stage(kt0, 0);

    for (int it = 0; it < NTILES; it++) {
        __syncthreads();   // drains vmcnt: tile `it` landed; other buf free
        if (it + 1 < NTILES) stage(kt0 + it + 1, (it + 1) & 1);
        const _Float16* kb_ = smem + (it & 1) * 4096;
        const _Float16* vb_ = smem + 8192 + (it & 1) * 4096;

        // S^T = K Q^T : one 32x32 tile, kv rows per C/D layout, q = ln
        f32x16 sc = (f32x16){};
        #pragma unroll
        for (int kb = 0; kb < 8; kb++) {
            int phys = (kb * 2 + h) ^ (ln & 15);
            f16x8 kf = *(const f16x8*)&kb_[ln * 128 + phys * 8];
            sc = mfma32(kf, qf[kb], sc);
        }

        // online softmax, per-lane scalar state (q = ln); 1 shuffle/reduce
        float t = sc[0];
        #pragma unroll
        for (int i = 1; i < 16; i++) t = fmaxf(t, sc[i]);
        t = fmaxf(t, __shfl_xor(t, 32));
        const float mnew  = fmaxf(m_run, t);
        const float alpha = exp2f(m_run - mnew);

        f16x4 phg[4];                 // group g: rows 8g+4h+{0..3}
        float ssum = 0.f;
        #pragma unroll
        for (int gi = 0; gi < 4; gi++) {
            #pragma unroll
            for (int e = 0; e < 4; e++) {
                float p = exp2f(sc[gi * 4 + e] - mnew);
                ssum += p;
                phg[gi][e] = (_Float16)p;
            }
        }
        ssum += __shfl_xor(ssum, 32);
        l_run = l_run * alpha + ssum;
        m_run = mnew;

        #pragma unroll
        for (int dvb = 0; dvb < 4; dvb++) o[dvb] *= alpha;

        // O^T += V^T P^T : B-frag of P^T via one shfl_xor(^32) per k-block
        #pragma unroll
        for (int kb2 = 0; kb2 < 2; kb2++) {
            f16x4 own0 = phg[2 * kb2], own1 = phg[2 * kb2 + 1];
            f16x4 send = h ? own0 : own1;
            unsigned long long sv = __builtin_bit_cast(unsigned long long, send);
            unsigned long long rv = __shfl_xor(sv, 32);
            f16x4 recv = __builtin_bit_cast(f16x4, rv);
            f16x4 lo = h ? recv : own0;
            f16x4 hi = h ? own1 : recv;
            f16x8 bf = __builtin_shufflevector(lo, hi, 0, 1, 2, 3, 4, 5, 6, 7);
            #pragma unroll
            for (int dvb = 0; dvb < 4; dvb++) {
                f16x8 vf = *(const f16x8*)&vb_[(dvb * 32 + ln) * 32 +
                                               (kb2 * 2 + h) * 8];
                o[dvb] = mfma32(vf, bf, o[dvb]);
            }
        }
    }

    // ---- epilogue: O^T -> wave-private LDS [32 q][132] -> coalesced stores
    __syncthreads();                       // all waves done with K/V buffers
    _Float16* pw = smem + wave * 4224;
    #pragma unroll
    for (int dvb = 0; dvb < 4; dvb++) {
        #pragma unroll
        for (int gi = 0; gi < 4; gi++) {
            f16x4 w4;
            #pragma unroll
            for (int e = 0; e < 4; e++) w4[e] = (_Float16)o[dvb][gi * 4 + e];
            *(f16x4*)&pw[ln * 132 + dvb * 32 + gi * 8 + h * 4] = w4;
        }
    }
    const size_t prow = (size_t)(z * 8 + b) * 2048 + q0 + wave * 32;
    __builtin_amdgcn_s_waitcnt(0);  // wave-private LDS round-trip
    #pragma unroll
    for (int p = 0; p < 2; p++) {
        int q = p * 16 + (lane >> 2), part = lane & 3;
        #pragma unroll
        for (int i2 = 0; i2 < 4; i2++) {
            f16x8 v8 = *(const f16x8*)&pw[q * 132 + part * 8 + i2 * 32];
            *(f16x8*)(opart + (prow + q) * 128 + part * 8 + i2 * 32) = v8;
        }
    }
    if (lane < 32) {
        float2 v; v.x = m_run; v.y = l_run;
        ml[prow + ln] = v;
    }
}

// ---------------------------------------------------------------------------
// Kernel 3: merge SPLIT partials. Block = 16 rows x 128 cols, grid 1024.
// ---------------------------------------------------------------------------
__global__ __launch_bounds__(256) void merge_kernel(
    const _Float16* __restrict__ opart, const float2* __restrict__ ml,
    float* __restrict__ out)
{
    const int t = threadIdx.x;
    const int r = t >> 4, cg = t & 15;
    const size_t row = (size_t)blockIdx.x * 16 + r;   // 0..16383 = b*2048+s

    float M = -1e30f;
    #pragma unroll
    for (int zi = 0; zi < SPLIT; zi++)
        M = fmaxf(M, ml[(size_t)zi * 16384 + row].x);
    float L = 0.f;
    float acc[8] = {0.f, 0.f, 0.f, 0.f, 0.f, 0.f, 0.f, 0.f};
    #pragma unroll
    for (int zi = 0; zi < SPLIT; zi++) {
        float2 p = ml[(size_t)zi * 16384 + row];
        float w = exp2f(p.x - M);
        L += w * p.y;
        f16x8 v = *(const f16x8*)&opart[((size_t)zi * 16384 + row) * 128 + cg * 8];
        #pragma unroll
        for (int j = 0; j < 8; j++) acc[j] += w * (float)v[j];
    }
    const float inv = 1.0f / L;
    float* op = out + row * 128 + cg * 8;
    f32x4 lo = (f32x4){acc[0] * inv, acc[1] * inv, acc[2] * inv, acc[3] * inv};
    f32x4 hi = (f32x4){acc[4] * inv, acc[5] * inv, acc[6] * inv, acc[7] * inv};
    *(f32x4*)op = lo;
    *(f32x4*)(op + 4) = hi;
}

// ---------------------------------------------------------------------------
extern "C" void kernel_launch(void* const* d_in, const int* in_sizes, int n_in,
                              void* d_out, int out_size, void* d_ws, size_t ws_size,
                              hipStream_t stream) {
    const float* xq = (const float*)d_in[0];
    const float* xk = (const float*)d_in[1];
    const float* xv = (const float*)d_in[2];
    const float* Wq = (const float*)d_in[3];
    const float* bq = (const float*)d_in[4];
    const float* Wk = (const float*)d_in[5];
    const float* bk = (const float*)d_in[6];
    const float* Wv = (const float*)d_in[7];
    const float* bv = (const float*)d_in[8];
    float* out = (float*)d_out;

    // ws layout: wt 192K | qo 4M | ko 4M | vt 4M | ml 1M | opart SPLIT*4M
    char* ws = (char*)d_ws;
    _Float16* wt    = (_Float16*)ws;
    _Float16* qo    = (_Float16*)(ws + 196608);
    _Float16* ko    = (_Float16*)(ws + 196608 + 4194304);
    _Float16* vt    = (_Float16*)(ws + 196608 + 2 * 4194304);
    float2*   ml    = (float2*)  (ws + 196608 + 3 * 4194304);
    _Float16* opart = (_Float16*)(ws + 196608 + 3 * 4194304 + 1048576);
    _Float16* vtmp  = opart;   // alias, lifetime disjoint

    hipLaunchKernelGGL(prep_weights, dim3(24), dim3(256), 0, stream,
                       Wq, Wk, Wv, wt);
    hipLaunchKernelGGL(proj_kernel, dim3(256, 3), dim3(256), 0, stream,
                       xq, xk, xv, wt, bq, bk, bv, qo, ko, vtmp);
    hipLaunchKernelGGL(transpose_v, dim3(32, 2, 8), dim3(256), 0, stream,
                       vtmp, vt);
    hipLaunchKernelGGL(attn_kernel, dim3(16 * 8 * SPLIT), dim3(256), 0, stream,
                       qo, ko, vt, opart, ml);
    hipLaunchKernelGGL(merge_kernel, dim3(1024), dim3(256), 0, stream,
                       opart, ml, out);
}

// Round 11
// 161.827 us; speedup vs baseline: 1.0347x; 1.0347x over previous
//
#include <hip/hip_runtime.h>
#include <stdint.h>

// Problem constants: B=8, S=2048, D=256, DK=DV=128
typedef float    f32x4  __attribute__((ext_vector_type(4)));
typedef float    f32x16 __attribute__((ext_vector_type(16)));
typedef _Float16 f16x8  __attribute__((ext_vector_type(8)));
typedef _Float16 f16x4  __attribute__((ext_vector_type(4)));
typedef unsigned int u32x4 __attribute__((ext_vector_type(4)));

#define SPLIT 4
#define NTILES 16  // 16 kv-tiles of 32 keys = 512 keys per block

__device__ __forceinline__ f32x4 mfma16(f16x8 a, f16x8 b, f32x4 c) {
    return __builtin_amdgcn_mfma_f32_16x16x32_f16(a, b, c, 0, 0, 0);
}
__device__ __forceinline__ f32x16 mfma32(f16x8 a, f16x8 b, f32x16 c) {
    return __builtin_amdgcn_mfma_f32_32x32x16_f16(a, b, c, 0, 0, 0);
}
// async global->LDS DMA, 16 B/lane; LDS dest = base + lane*16 (wave-uniform base)
__device__ __forceinline__ void gll16(const _Float16* g, _Float16* l) {
    __builtin_amdgcn_global_load_lds(
        (const __attribute__((address_space(1))) void*)g,
        (__attribute__((address_space(3))) void*)l, 16, 0, 0);
}

// ---------------------------------------------------------------------------
// Kernel 0: transpose+convert W[256][128] f32 -> Wt[w][n][k]=[3][128][256] f16
// ---------------------------------------------------------------------------
__global__ __launch_bounds__(256) void prep_weights(
    const float* __restrict__ Wq, const float* __restrict__ Wk,
    const float* __restrict__ Wv, _Float16* __restrict__ wt) {
    __shared__ float Ls[64 * 65];
    const int bx = blockIdx.x;
    const int w  = bx >> 3, t = bx & 7;
    const int k0 = (t >> 1) * 64, n0 = (t & 1) * 64;
    const float* W = (w == 0) ? Wq : (w == 1) ? Wk : Wv;
    const int tid = threadIdx.x;
    #pragma unroll
    for (int i = 0; i < 16; i++) {
        int idx = i * 256 + tid;
        int r = idx >> 6, c = idx & 63;
        Ls[r * 65 + c] = W[(k0 + r) * 128 + n0 + c];
    }
    __syncthreads();
    #pragma unroll
    for (int i = 0; i < 16; i++) {
        int idx = i * 256 + tid;
        int r2 = idx >> 6, c2 = idx & 63;
        wt[w * 32768 + (n0 + r2) * 256 + k0 + c2] = (_Float16)Ls[c2 * 65 + r2];
    }
}

// ---------------------------------------------------------------------------
// Kernel 1: projections. Modes 0/1 (q,k): barrier-free, row-major stores.
// Mode 2 (v): epilogue transposes the 64x128 C-tile through LDS and stores
// vt[b][dv][s] directly with coalesced 128-B rows (kills transpose_v kernel).
// ---------------------------------------------------------------------------
__global__ __launch_bounds__(256) void proj_kernel(
    const float* __restrict__ xq, const float* __restrict__ xk,
    const float* __restrict__ xv, const _Float16* __restrict__ wt,
    const float* __restrict__ bq, const float* __restrict__ bk,
    const float* __restrict__ bv,
    _Float16* __restrict__ qo, _Float16* __restrict__ ko,
    _Float16* __restrict__ vt)
{
    const int mode = blockIdx.y;
    const float*    X    = mode == 0 ? xq : mode == 1 ? xk : xv;
    const float*    bias = mode == 0 ? bq : mode == 1 ? bk : bv;
    const _Float16* W    = wt + mode * 32768;

    __shared__ __align__(16) _Float16 Ls[128 * 66];   // mode-2 transpose tile

    const int tid  = threadIdx.x;
    const int wave = tid >> 6, lane = tid & 63;
    const int ln   = lane & 15, qd = lane >> 4;
    const int row0 = blockIdx.x * 64 + wave * 16;

    const float*    xrow = X + (size_t)(row0 + ln) * 256 + qd * 8;
    const _Float16* wb   = W + ln * 256 + qd * 8;

    f32x4 acc[8];
    #pragma unroll
    for (int i = 0; i < 8; i++) acc[i] = (f32x4){0.f, 0.f, 0.f, 0.f};

    #pragma unroll
    for (int kk = 0; kk < 8; kk++) {
        f32x4 a0 = *(const f32x4*)(xrow + kk * 32);
        f32x4 a1 = *(const f32x4*)(xrow + kk * 32 + 4);
        f16x8 af;
        af[0] = (_Float16)a0[0]; af[1] = (_Float16)a0[1];
        af[2] = (_Float16)a0[2]; af[3] = (_Float16)a0[3];
        af[4] = (_Float16)a1[0]; af[5] = (_Float16)a1[1];
        af[6] = (_Float16)a1[2]; af[7] = (_Float16)a1[3];
        #pragma unroll
        for (int nt = 0; nt < 8; nt++) {
            f16x8 bf = *(const f16x8*)(wb + nt * 4096 + kk * 32);
            acc[nt] = mfma16(af, bf, acc[nt]);
        }
    }

    const float SC = 0.08838834764831845f * 1.4426950408889634f;
    if (mode != 2) {
        _Float16* Y = mode == 0 ? qo : ko;
        #pragma unroll
        for (int nt = 0; nt < 8; nt++) {
            int col = nt * 16 + ln;
            float bb = bias[col];
            #pragma unroll
            for (int r = 0; r < 4; r++) {
                int orow = row0 + qd * 4 + r;
                float val = acc[nt][r] + bb;
                if (mode == 0) val *= SC;
                Y[(size_t)orow * 128 + col] = (_Float16)val;
            }
        }
    } else {
        // transpose through LDS: Ls[col][srow], then coalesced vt stores
        #pragma unroll
        for (int nt = 0; nt < 8; nt++) {
            int col = nt * 16 + ln;
            float bb = bias[col];
            #pragma unroll
            for (int r = 0; r < 4; r++) {
                int srow = wave * 16 + qd * 4 + r;
                Ls[col * 66 + srow] = (_Float16)(acc[nt][r] + bb);
            }
        }
        __syncthreads();
        const int bb2 = row0 >> 11;            // batch
        const int s0  = (blockIdx.x * 64) & 2047;
        #pragma unroll
        for (int i = 0; i < 4; i++) {
            int g  = i * 256 + tid;            // granule 0..1023
            int dv = g >> 3, off = (g & 7) * 8;
            f16x8 v8 = *(const f16x8*)&Ls[dv * 66 + off];
            *(f16x8*)(vt + ((size_t)(bb2 * 128 + dv)) * 2048 + s0 + off) = v8;
        }
    }
}

// ---------------------------------------------------------------------------
// Kernel 2: flash attention, 32x32x16 MFMA, S^T = K Q^T. R10 core with:
// (a) all LDS read/staging offsets precomputed (loop-invariant) and the
//     double-buffer toggle made a compile-time constant via 2x unroll,
// (b) ballot-skip of the o-rescale when no lane's max moved,
// (c) SPLIT 4 (halves opart traffic; grid 512 = 2 blocks/CU, one round).
// K source XOR-swizzled per granule (unswizzled rows are 256B-strided ->
// 32-way bank conflicts). launch_bounds(256,3): 170-reg budget, no spill.
// ---------------------------------------------------------------------------
__global__ __launch_bounds__(256, 3) void attn_kernel(
    const _Float16* __restrict__ qp, const _Float16* __restrict__ kp,
    const _Float16* __restrict__ vtp, _Float16* __restrict__ opart,
    float2* __restrict__ ml)
{
    // decode: xcd fastest (round-robin pin), then q0, then group-high
    const int bid = blockIdx.x;
    const int gx  = bid & 7;
    const int q0i = (bid >> 3) & 15;
    const int gg  = bid >> 7;            // 0..3
    const int g   = gg * 8 + gx;         // 0..31 = b*SPLIT+z
    const int b   = g >> 2;
    const int z   = g & 3;
    const int q0  = q0i * 128;

    const int tid  = threadIdx.x;
    const int wave = tid >> 6, lane = tid & 63;
    const int ln   = lane & 31, h = lane >> 5;

    // staging: K dbuf at f16 ofs 0/4096 (32x128), V dbuf at 8192/12288
    // (128x32); epilogue reuses 0..16895 as 4 x (32 q x 132) per wave.
    __shared__ __align__(16) _Float16 smem[16896];

    // ---- precomputed loop-invariant offsets ----
    int koff[8], voff[2][4];
    #pragma unroll
    for (int kb = 0; kb < 8; kb++)
        koff[kb] = ln * 128 + (((kb * 2 + h) ^ (ln & 15)) * 8);
    #pragma unroll
    for (int kb2 = 0; kb2 < 2; kb2++)
        #pragma unroll
        for (int dvb = 0; dvb < 4; dvb++)
            voff[kb2][dvb] = 8192 + (dvb * 32 + ln) * 32 + (kb2 * 2 + h) * 8;
    int kidx[2], vidx[2], dst[2];
    #pragma unroll
    for (int j = 0; j < 2; j++) {
        int p = wave * 128 + j * 64 + lane;
        int r = p >> 4, c = p & 15;
        kidx[j] = r * 128 + ((c ^ (r & 15)) * 8);
        vidx[j] = (p >> 2) * 2048 + (p & 3) * 8;
        dst[j]  = (wave * 128 + j * 64) * 8;
    }

    // Q fragments: B-operand of S^T. qf[kb][j] = Q[q=ln][d=kb*16+h*8+j]
    const _Float16* qbase =
        qp + (size_t)(b * 2048 + q0 + wave * 32 + ln) * 128 + h * 8;
    f16x8 qf[8];
    #pragma unroll
    for (int kb = 0; kb < 8; kb++) qf[kb] = *(const f16x8*)(qbase + kb * 16);

    f32x16 o[4];                      // O^T: dv = dvb*32+(i&3)+8*(i>>2)+4h, q=ln
    #pragma unroll
    for (int i = 0; i < 4; i++) o[i] = (f32x16){};
    float m_run = -1e30f, l_run = 0.f;

    const _Float16* kbase = kp + (size_t)b * 2048 * 128;
    const _Float16* vbase = vtp + (size_t)b * 128 * 2048;
    const int kt0 = z * NTILES;

    auto stage = [&](int kt, int buf) {
        const _Float16* ks = kbase + (size_t)kt * 4096;
        const _Float16* vs = vbase + kt * 32;
        _Float16* kdst = smem + buf * 4096;
        _Float16* vdst = smem + 8192 + buf * 4096;
        #pragma unroll
        for (int j = 0; j < 2; j++) {
            gll16(ks + kidx[j], kdst + dst[j]);
            gll16(vs + vidx[j], vdst + dst[j]);
        }
    };

    auto do_tile = [&](const int BUF) {   // BUF literal -> offsets fold
        const int KO = BUF * 4096, VO = BUF * 4096;
        // S^T = K Q^T : one 32x32 tile, kv rows per C/D layout, q = ln
        f32x16 sc = (f32x16){};
        #pragma unroll
        for (int kb = 0; kb < 8; kb++) {
            f16x8 kf = *(const f16x8*)&smem[KO + koff[kb]];
            sc = mfma32(kf, qf[kb], sc);
        }
        // online softmax, per-lane scalar state (q = ln); 1 shuffle/reduce
        float t = sc[0];
        #pragma unroll
        for (int i = 1; i < 16; i++) t = fmaxf(t, sc[i]);
        t = fmaxf(t, __shfl_xor(t, 32));
        const float mnew  = fmaxf(m_run, t);
        const float alpha = exp2f(m_run - mnew);

        f16x4 phg[4];                 // group g: rows 8g+4h+{0..3}
        float ssum = 0.f;
        #pragma unroll
        for (int gi = 0; gi < 4; gi++) {
            #pragma unroll
            for (int e = 0; e < 4; e++) {
                float p = exp2f(sc[gi * 4 + e] - mnew);
                ssum += p;
                phg[gi][e] = (_Float16)p;
            }
        }
        ssum += __shfl_xor(ssum, 32);
        l_run = l_run * alpha + ssum;
        m_run = mnew;

        if (__any(alpha < 1.0f)) {    // skip rescale when max unchanged
            #pragma unroll
            for (int dvb = 0; dvb < 4; dvb++) o[dvb] *= alpha;
        }

        // O^T += V^T P^T : B-frag of P^T via one shfl_xor(^32) per k-block
        #pragma unroll
        for (int kb2 = 0; kb2 < 2; kb2++) {
            f16x4 own0 = phg[2 * kb2], own1 = phg[2 * kb2 + 1];
            f16x4 send = h ? own0 : own1;
            unsigned long long sv = __builtin_bit_cast(unsigned long long, send);
            unsigned long long rv = __shfl_xor(sv, 32);
            f16x4 recv = __builtin_bit_cast(f16x4, rv);
            f16x4 lo = h ? recv : own0;
            f16x4 hi = h ? own1 : recv;
            f16x8 bf = __builtin_shufflevector(lo, hi, 0, 1, 2, 3, 4, 5, 6, 7);
            #pragma unroll
            for (int dvb = 0; dvb < 4; dvb++) {
                f16x8 vf = *(const f16x8*)&smem[VO + voff[kb2][dvb]];
                o[dvb] = mfma32(vf, bf, o[dvb]);
            }
        }
    };

    stage(kt0, 0);
    #pragma unroll 1
    for (int ht = 0; ht < NTILES / 2; ht++) {
        __syncthreads();                           // tile 2ht landed
        if (2 * ht + 1 < NTILES) stage(kt0 + 2 * ht + 1, 1);
        do_tile(0);
        __syncthreads();                           // tile 2ht+1 landed
        if (2 * ht + 2 < NTILES) stage(kt0 + 2 * ht + 2, 0);
        do_tile(1);
    }

    // ---- epilogue: O^T -> wave-private LDS [32 q][132] -> coalesced stores
    __syncthreads();                       // all waves done with K/V buffers
    _Float16* pw = smem + wave * 4224;
    #pragma unroll
    for (int dvb = 0; dvb < 4; dvb++) {
        #pragma unroll
        for (int gi = 0; gi < 4; gi++) {
            f16x4 w4;
            #pragma unroll
            for (int e = 0; e < 4; e++) w4[e] = (_Float16)o[dvb][gi * 4 + e];
            *(f16x4*)&pw[ln * 132 + dvb * 32 + gi * 8 + h * 4] = w4;
        }
    }
    const size_t prow = (size_t)(z * 8 + b) * 2048 + q0 + wave * 32;
    __builtin_amdgcn_s_waitcnt(0);  // wave-private LDS round-trip
    #pragma unroll
    for (int p = 0; p < 2; p++) {
        int q = p * 16 + (lane >> 2), part = lane & 3;
        #pragma unroll
        for (int i2 = 0; i2 < 4; i2++) {
            f16x8 v8 = *(const f16x8*)&pw[q * 132 + part * 8 + i2 * 32];
            *(f16x8*)(opart + (prow + q) * 128 + part * 8 + i2 * 32) = v8;
        }
    }
    if (lane < 32) {
        float2 v; v.x = m_run; v.y = l_run;
        ml[prow + ln] = v;
    }
}

// ---------------------------------------------------------------------------
// Kernel 3: merge SPLIT partials. Block = 16 rows x 128 cols, grid 1024.
// ---------------------------------------------------------------------------
__global__ __launch_bounds__(256) void merge_kernel(
    const _Float16* __restrict__ opart, const float2* __restrict__ ml,
    float* __restrict__ out)
{
    const int t = threadIdx.x;
    const int r = t >> 4, cg = t & 15;
    const size_t row = (size_t)blockIdx.x * 16 + r;   // 0..16383 = b*2048+s

    float M = -1e30f;
    #pragma unroll
    for (int zi = 0; zi < SPLIT; zi++)
        M = fmaxf(M, ml[(size_t)zi * 16384 + row].x);
    float L = 0.f;
    float acc[8] = {0.f, 0.f, 0.f, 0.f, 0.f, 0.f, 0.f, 0.f};
    #pragma unroll
    for (int zi = 0; zi < SPLIT; zi++) {
        float2 p = ml[(size_t)zi * 16384 + row];
        float w = exp2f(p.x - M);
        L += w * p.y;
        f16x8 v = *(const f16x8*)&opart[((size_t)zi * 16384 + row) * 128 + cg * 8];
        #pragma unroll
        for (int j = 0; j < 8; j++) acc[j] += w * (float)v[j];
    }
    const float inv = 1.0f / L;
    float* op = out + row * 128 + cg * 8;
    f32x4 lo = (f32x4){acc[0] * inv, acc[1] * inv, acc[2] * inv, acc[3] * inv};
    f32x4 hi = (f32x4){acc[4] * inv, acc[5] * inv, acc[6] * inv, acc[7] * inv};
    *(f32x4*)op = lo;
    *(f32x4*)(op + 4) = hi;
}

// ---------------------------------------------------------------------------
extern "C" void kernel_launch(void* const* d_in, const int* in_sizes, int n_in,
                              void* d_out, int out_size, void* d_ws, size_t ws_size,
                              hipStream_t stream) {
    const float* xq = (const float*)d_in[0];
    const float* xk = (const float*)d_in[1];
    const float* xv = (const float*)d_in[2];
    const float* Wq = (const float*)d_in[3];
    const float* bq = (const float*)d_in[4];
    const float* Wk = (const float*)d_in[5];
    const float* bk = (const float*)d_in[6];
    const float* Wv = (const float*)d_in[7];
    const float* bv = (const float*)d_in[8];
    float* out = (float*)d_out;

    // ws layout: wt 192K | qo 4M | ko 4M | vt 4M | ml 1M | opart SPLIT*4M
    char* ws = (char*)d_ws;
    _Float16* wt    = (_Float16*)ws;
    _Float16* qo    = (_Float16*)(ws + 196608);
    _Float16* ko    = (_Float16*)(ws + 196608 + 4194304);
    _Float16* vt    = (_Float16*)(ws + 196608 + 2 * 4194304);
    float2*   ml    = (float2*)  (ws + 196608 + 3 * 4194304);
    _Float16* opart = (_Float16*)(ws + 196608 + 3 * 4194304 + 1048576);

    hipLaunchKernelGGL(prep_weights, dim3(24), dim3(256), 0, stream,
                       Wq, Wk, Wv, wt);
    hipLaunchKernelGGL(proj_kernel, dim3(256, 3), dim3(256), 0, stream,
                       xq, xk, xv, wt, bq, bk, bv, qo, ko, vt);
    hipLaunchKernelGGL(attn_kernel, dim3(16 * 8 * SPLIT), dim3(256), 0, stream,
                       qo, ko, vt, opart, ml);
    hipLaunchKernelGGL(merge_kernel, dim3(1024), dim3(256), 0, stream,
                       opart, ml, out);
}